// Round 3
// baseline (10799.157 us; speedup 1.0000x reference)
//
#include <hip/hip_runtime.h>
#include <hip/hip_bf16.h>
#include <hip/hip_fp16.h>

using half2_t = __attribute__((ext_vector_type(2))) _Float16;
using half4_t = __attribute__((ext_vector_type(4))) _Float16;
using half8_t = __attribute__((ext_vector_type(8))) _Float16;
using f32x4   = __attribute__((ext_vector_type(4))) float;

#define B_   64
#define T_   2048
#define D_   256
#define U_   256
#define NG   768      // 3U
#define TC   512      // T-chunk
#define NCHUNK (T_/TC)
#define NB   16       // batches per scan block
#define NBLK (B_/NB)  // 4 scan blocks

typedef const __attribute__((address_space(1))) void* gptr_t;
typedef __attribute__((address_space(3))) void* lptr_t;

__device__ __forceinline__ float sigf(float x) { return 1.f / (1.f + __expf(-x)); }

// ---------------- conversions ----------------

__global__ void conv_x_chunk(const float* __restrict__ x, _Float16* __restrict__ xh, int t0) {
  size_t idx = ((size_t)blockIdx.x * 256 + threadIdx.x) * 8;
  int b   = (int)(idx >> 17);        // TC*D = 131072 = 2^17
  int rem = (int)(idx & 131071);
  const float4* p = (const float4*)(x + ((size_t)(b * T_ + t0)) * D_ + rem);
  float4 v0 = p[0], v1 = p[1];
  half8_t o;
  o[0] = (_Float16)v0.x; o[1] = (_Float16)v0.y; o[2] = (_Float16)v0.z; o[3] = (_Float16)v0.w;
  o[4] = (_Float16)v1.x; o[5] = (_Float16)v1.y; o[6] = (_Float16)v1.z; o[7] = (_Float16)v1.w;
  *(half8_t*)(xh + idx) = o;
}

// src [256][768] f32 -> dst [768][256] f16 (transpose + convert)
__global__ void conv_T(const float* __restrict__ src, _Float16* __restrict__ dst) {
  int idx = blockIdx.x * 256 + threadIdx.x;
  int d = idx / NG;
  int j = idx - d * NG;
  dst[j * 256 + d] = (_Float16)src[idx];
}

// ---------------- phase 1: xw = x @ kernel + bias, scattered into scan layout ----------------
// A [M][256] f16; BT [768][256] f16; out: xwl [NBLK][512][NB][768] f16, col-swizzled (c ^ ((bi&7)<<3))
#define BM 128
#define BN 128

__global__ __launch_bounds__(256, 2) void gemm16(
    const _Float16* __restrict__ A,
    const _Float16* __restrict__ BT,
    const float* __restrict__ bias,
    _Float16* __restrict__ xwl)
{
  __shared__ alignas(16) _Float16 As[BM * 32];
  __shared__ alignas(16) _Float16 Bs[BN * 32];
  const int tid = threadIdx.x, l = tid & 63, w = tid >> 6;
  const int NT = NG / BN;                       // 6
  const int mt = blockIdx.x / NT, nt = blockIdx.x % NT;
  const char* Ab = (const char*)A  + (size_t)mt * BM * 512;
  const char* Bb = (const char*)BT + (size_t)nt * BN * 512;
  const int wm = (w & 1) * 64, wn = (w >> 1) * 64;
  f32x4 acc[4][4] = {};

  for (int kt = 0; kt < 8; ++kt) {
    #pragma unroll
    for (int s = 0; s < 2; ++s) {
      int c = tid + s * 256;
      int row = c >> 2, g = c & 3;
      int gs = g ^ ((row >> 1) & 3);
      __builtin_amdgcn_global_load_lds(
        (gptr_t)(Ab + (size_t)row * 512 + kt * 64 + gs * 16),
        (lptr_t)((char*)As + c * 16), 16, 0, 0);
    }
    #pragma unroll
    for (int s = 0; s < 2; ++s) {
      int c = tid + s * 256;
      int row = c >> 2, g = c & 3;
      int gs = g ^ ((row >> 1) & 3);
      __builtin_amdgcn_global_load_lds(
        (gptr_t)(Bb + (size_t)row * 512 + kt * 64 + gs * 16),
        (lptr_t)((char*)Bs + c * 16), 16, 0, 0);
    }
    __syncthreads();

    half8_t av[4], bv[4];
    #pragma unroll
    for (int m = 0; m < 4; ++m) {
      int row = wm + m * 16 + (l & 15);
      int off = row * 64 + (((l >> 4) ^ ((row >> 1) & 3)) << 4);
      av[m] = *(const half8_t*)((const char*)As + off);
    }
    #pragma unroll
    for (int n = 0; n < 4; ++n) {
      int row = wn + n * 16 + (l & 15);
      int off = row * 64 + (((l >> 4) ^ ((row >> 1) & 3)) << 4);
      bv[n] = *(const half8_t*)((const char*)Bs + off);
    }
    #pragma unroll
    for (int m = 0; m < 4; ++m)
      #pragma unroll
      for (int n = 0; n < 4; ++n)
        acc[m][n] = __builtin_amdgcn_mfma_f32_16x16x32_f16(av[m], bv[n], acc[m][n], 0, 0, 0);
    __syncthreads();
  }

  // epilogue: scatter into scan layout with bias add + col swizzle
  int m0 = mt * BM, n0 = nt * BN;
  #pragma unroll
  for (int m = 0; m < 4; ++m) {
    #pragma unroll
    for (int n = 0; n < 4; ++n) {
      int c = n0 + wn + n * 16 + (l & 15);
      float bc = bias[c];
      #pragma unroll
      for (int q = 0; q < 4; ++q) {
        int arow = m0 + wm + m * 16 + ((l >> 4) * 4 + q);   // = b*512 + t
        int bidx = arow >> 9, tloc = arow & 511;
        int bi = bidx & 15, blk = bidx >> 4;
        size_t dst = (((size_t)(blk * 512 + tloc) * NB) + bi) * NG + (c ^ ((bi & 7) << 3));
        xwl[dst] = (_Float16)(acc[m][n][q] + bc);
      }
    }
  }
}

// ---------------- phase 2: MFMA-batched GRU scan + deferred LayerNorm ----------------
// 4 blocks x 512 threads (8 waves). Block handles batches blk*16..+15.
// Per step: gates[768x16] = recT(768x256) x H(256x16) via 48 MFMA tiles, K=8 slices.
// Wave w owns u-tiles {2w,2w+1}: M-tiles {2w,2w+1, 16+2w,17+2w, 32+2w,33+2w}
// -> lane (bi=l&15, hi=l>>4) holds z/r/hh AND h for u = (2w+tt)*16+hi*4+q, batch bi.
__global__ __launch_bounds__(512, 1) void scan_mfma(
    const _Float16* __restrict__ xwl,   // [NBLK][512][NB][768] swizzled, bias added
    const _Float16* __restrict__ rT,    // [768][256]
    const float* __restrict__ gamma,
    const float* __restrict__ beta,
    float* __restrict__ out,            // [64][2048][256] f32
    float* __restrict__ hg,             // [64][256] f32
    int t0)
{
  const int blk = blockIdx.x;
  const int tid = threadIdx.x;
  const int w  = tid >> 6;
  const int l  = tid & 63;
  const int bi = l & 15;
  const int hi = l >> 4;
  const int bg = blk * NB + bi;                 // global batch

  __shared__ alignas(16) _Float16 Hsw[2][NB * 256];   // 2 x 8KB, granule-swizzled
  __shared__ alignas(16) _Float16 XWb[2][NB * NG];    // 2 x 24KB, pre-swizzled
  __shared__ float red[2][8][NB][2];

  // rec A-frag pointers: 6 tiles, addr = rT + (mtile*16 + bi)*256 + hi*8 (f16 units); +ks*32 folded
  const _Float16* rp[6];
  #pragma unroll
  for (int g = 0; g < 3; ++g) {
    #pragma unroll
    for (int tt = 0; tt < 2; ++tt) {
      int mtile = g * 16 + 2 * w + tt;
      rp[g * 2 + tt] = rT + ((size_t)(mtile * 16 + bi)) * 256 + hi * 8;
    }
  }

  const int u0 = (2 * w) * 16 + hi * 4;        // tt=0; tt=1 adds +16
  float4 gm0 = *(const float4*)(gamma + u0);
  float4 gm1 = *(const float4*)(gamma + u0 + 16);
  float4 bt0 = *(const float4*)(beta + u0);
  float4 bt1 = *(const float4*)(beta + u0 + 16);

  // persistent h in f32 regs: hr[tt*4+q]
  float hr[8];
  if (t0 == 0) {
    #pragma unroll
    for (int i = 0; i < 8; ++i) hr[i] = 0.f;
  } else {
    float4 h0 = *(const float4*)(hg + (size_t)bg * 256 + u0);
    float4 h1 = *(const float4*)(hg + (size_t)bg * 256 + u0 + 16);
    hr[0]=h0.x; hr[1]=h0.y; hr[2]=h0.z; hr[3]=h0.w;
    hr[4]=h1.x; hr[5]=h1.y; hr[6]=h1.z; hr[7]=h1.w;
  }

  // H LDS write helper offsets (bytes): bi*512 + ((gran ^ (bi&7))<<4) + (u0b&7)*2
  auto h_off = [&](int tt) {
    int u0b = u0 + tt * 16;
    int gran = u0b >> 3;
    return bi * 512 + (((gran ^ (bi & 7))) << 4) + ((u0b & 7) << 1);
  };
  // write initial H into buf 0
  {
    half4_t p0, p1;
    p0[0]=(_Float16)hr[0]; p0[1]=(_Float16)hr[1]; p0[2]=(_Float16)hr[2]; p0[3]=(_Float16)hr[3];
    p1[0]=(_Float16)hr[4]; p1[1]=(_Float16)hr[5]; p1[2]=(_Float16)hr[6]; p1[3]=(_Float16)hr[7];
    *(half4_t*)((char*)&Hsw[0][0] + h_off(0)) = p0;
    *(half4_t*)((char*)&Hsw[0][0] + h_off(1)) = p1;
  }
  // stage XW page for t=0
  const char* xwb = (const char*)xwl + (size_t)blk * 512 * NB * NG * 2;
  #pragma unroll
  for (int i = 0; i < 3; ++i)
    __builtin_amdgcn_global_load_lds(
      (gptr_t)(xwb + 0 * (NB * NG * 2) + tid * 16 + i * 8192),
      (lptr_t)((char*)&XWb[0][0] + tid * 16 + i * 8192), 16, 0, 0);
  __syncthreads();

  float* outp = out + ((size_t)bg * T_ + t0) * U_;

  for (int t = 0; t < TC; ++t) {
    const int cur = t & 1, nxt = cur ^ 1;

    // prefetch next XW page (double-buffered; prev readers of nxt done at last barrier)
    int tn = (t + 1 < TC) ? (t + 1) : t;
    #pragma unroll
    for (int i = 0; i < 3; ++i)
      __builtin_amdgcn_global_load_lds(
        (gptr_t)(xwb + (size_t)tn * (NB * NG * 2) + tid * 16 + i * 8192),
        (lptr_t)((char*)&XWb[nxt][0] + tid * 16 + i * 8192), 16, 0, 0);

    // ---- deferred LayerNorm of step t-1 (uses hr before update) ----
    if (t > 0) {
      const float* rd = &red[(t - 1) & 1][0][bi][0];
      float s  = rd[hi * NB * 2]       + rd[(hi + 4) * NB * 2];
      float s2 = rd[hi * NB * 2 + 1]   + rd[(hi + 4) * NB * 2 + 1];
      s  += __shfl_xor(s, 16);  s  += __shfl_xor(s, 32);
      s2 += __shfl_xor(s2, 16); s2 += __shfl_xor(s2, 32);
      float mu = s * (1.f / 256.f);
      float var = s2 * (1.f / 256.f) - mu * mu;
      float rs = rsqrtf(var + 1e-6f);
      float4 o0, o1;
      o0.x = (hr[0]-mu)*rs*gm0.x + bt0.x; o0.y = (hr[1]-mu)*rs*gm0.y + bt0.y;
      o0.z = (hr[2]-mu)*rs*gm0.z + bt0.z; o0.w = (hr[3]-mu)*rs*gm0.w + bt0.w;
      o1.x = (hr[4]-mu)*rs*gm1.x + bt1.x; o1.y = (hr[5]-mu)*rs*gm1.y + bt1.y;
      o1.z = (hr[6]-mu)*rs*gm1.z + bt1.z; o1.w = (hr[7]-mu)*rs*gm1.w + bt1.w;
      *(float4*)(outp + (size_t)(t - 1) * U_ + u0) = o0;
      *(float4*)(outp + (size_t)(t - 1) * U_ + u0 + 16) = o1;
    }

    // ---- K-loop: 8 slices, software-pipelined rec loads ----
    f32x4 acc[6] = {};
    const char* hbase = (const char*)&Hsw[cur][0];
    half8_t fA[2][6], fB[2];
    // B-frag byte addr for slice ks: bi*512 + (((ks*4+hi) ^ (bi&7))<<4)
    #pragma unroll
    for (int g = 0; g < 6; ++g) fA[0][g] = *(const half8_t*)(rp[g] + 0 * 32);
    fB[0] = *(const half8_t*)(hbase + bi * 512 + ((((0 * 4 + hi) ^ (bi & 7))) << 4));
    #pragma unroll
    for (int ks = 0; ks < 8; ++ks) {
      const int cb = ks & 1, nb = cb ^ 1;
      if (ks < 7) {
        #pragma unroll
        for (int g = 0; g < 6; ++g) fA[nb][g] = *(const half8_t*)(rp[g] + (ks + 1) * 32);
        fB[nb] = *(const half8_t*)(hbase + bi * 512 + (((((ks + 1) * 4 + hi) ^ (bi & 7))) << 4));
      }
      #pragma unroll
      for (int g = 0; g < 6; ++g)
        acc[g] = __builtin_amdgcn_mfma_f32_16x16x32_f16(fA[cb][g], fB[cb], acc[g], 0, 0, 0);
    }

    // ---- gates: read xw (swizzled LDS), nonlinearities, h update ----
    const char* xwp = (const char*)&XWb[cur][0];
    auto xw_off = [&](int gate, int tt) {
      int c = gate * 256 + (2 * w + tt) * 16 + hi * 4;
      return bi * 1536 + (((c >> 3) ^ (bi & 7)) << 4) + ((c & 7) << 1);
    };
    half4_t xz0 = *(const half4_t*)(xwp + xw_off(0, 0));
    half4_t xz1 = *(const half4_t*)(xwp + xw_off(0, 1));
    half4_t xr0 = *(const half4_t*)(xwp + xw_off(1, 0));
    half4_t xr1 = *(const half4_t*)(xwp + xw_off(1, 1));
    half4_t xg0 = *(const half4_t*)(xwp + xw_off(2, 0));
    half4_t xg1 = *(const half4_t*)(xwp + xw_off(2, 1));

    float s = 0.f, s2 = 0.f;
    half4_t hp0, hp1;
    #pragma unroll
    for (int q = 0; q < 4; ++q) {
      {
        float z = sigf(acc[0][q] + (float)xz0[q]);
        float r = sigf(acc[2][q] + (float)xr0[q]);
        float gh = acc[4][q] + (float)xg0[q];
        float y = r * gh + (1.f - r) * hr[q];
        float th = 2.f * sigf(2.f * y) - 1.f;
        float hn = (1.f - z) * th + z * hr[q];
        hr[q] = hn; hp0[q] = (_Float16)hn;
        s += hn; s2 += hn * hn;
      }
      {
        float z = sigf(acc[1][q] + (float)xz1[q]);
        float r = sigf(acc[3][q] + (float)xr1[q]);
        float gh = acc[5][q] + (float)xg1[q];
        float y = r * gh + (1.f - r) * hr[4 + q];
        float th = 2.f * sigf(2.f * y) - 1.f;
        float hn = (1.f - z) * th + z * hr[4 + q];
        hr[4 + q] = hn; hp1[q] = (_Float16)hn;
        s += hn; s2 += hn * hn;
      }
    }
    // write h_new to next H buffer (swizzled)
    *(half4_t*)((char*)&Hsw[nxt][0] + h_off(0)) = hp0;
    *(half4_t*)((char*)&Hsw[nxt][0] + h_off(1)) = hp1;

    // LN partial sums: reduce over hi-groups within wave
    s  += __shfl_xor(s, 16);  s  += __shfl_xor(s, 32);
    s2 += __shfl_xor(s2, 16); s2 += __shfl_xor(s2, 32);
    if (hi == 0) { red[cur][w][bi][0] = s; red[cur][w][bi][1] = s2; }

    __syncthreads();
  }

  // drain: LN of last step + persist h
  {
    const float* rd = &red[(TC - 1) & 1][0][bi][0];
    float s  = rd[hi * NB * 2]     + rd[(hi + 4) * NB * 2];
    float s2 = rd[hi * NB * 2 + 1] + rd[(hi + 4) * NB * 2 + 1];
    s  += __shfl_xor(s, 16);  s  += __shfl_xor(s, 32);
    s2 += __shfl_xor(s2, 16); s2 += __shfl_xor(s2, 32);
    float mu = s * (1.f / 256.f);
    float var = s2 * (1.f / 256.f) - mu * mu;
    float rs = rsqrtf(var + 1e-6f);
    float4 o0, o1;
    o0.x = (hr[0]-mu)*rs*gm0.x + bt0.x; o0.y = (hr[1]-mu)*rs*gm0.y + bt0.y;
    o0.z = (hr[2]-mu)*rs*gm0.z + bt0.z; o0.w = (hr[3]-mu)*rs*gm0.w + bt0.w;
    o1.x = (hr[4]-mu)*rs*gm1.x + bt1.x; o1.y = (hr[5]-mu)*rs*gm1.y + bt1.y;
    o1.z = (hr[6]-mu)*rs*gm1.z + bt1.z; o1.w = (hr[7]-mu)*rs*gm1.w + bt1.w;
    *(float4*)(outp + (size_t)(TC - 1) * U_ + u0) = o0;
    *(float4*)(outp + (size_t)(TC - 1) * U_ + u0 + 16) = o1;
    float4 h0, h1;
    h0.x=hr[0]; h0.y=hr[1]; h0.z=hr[2]; h0.w=hr[3];
    h1.x=hr[4]; h1.y=hr[5]; h1.z=hr[6]; h1.w=hr[7];
    *(float4*)(hg + (size_t)bg * 256 + u0) = h0;
    *(float4*)(hg + (size_t)bg * 256 + u0 + 16) = h1;
  }
}

// ---------------- launcher ----------------
extern "C" void kernel_launch(void* const* d_in, const int* in_sizes, int n_in,
                              void* d_out, int out_size, void* d_ws, size_t ws_size,
                              hipStream_t stream) {
  const float* x     = (const float*)d_in[0];
  const float* kern  = (const float*)d_in[1];
  const float* rec   = (const float*)d_in[2];
  const float* bias  = (const float*)d_in[3];
  const float* gamma = (const float*)d_in[4];
  const float* beta  = (const float*)d_in[5];
  float* out = (float*)d_out;
  char* ws = (char*)d_ws;

  _Float16* xwl = (_Float16*)(ws);                 // 4*512*16*768*2 = 50,331,648 B
  _Float16* xhc = (_Float16*)(ws + 50331648);      // 64*512*256*2 = 16,777,216 B
  _Float16* kT  = (_Float16*)(ws + 67108864);      // 393,216 B
  _Float16* rT  = (_Float16*)(ws + 67502080);      // 393,216 B
  float*    hg  = (float*)   (ws + 67895296);      // 65,536 B

  conv_T<<<768, 256, 0, stream>>>(kern, kT);
  conv_T<<<768, 256, 0, stream>>>(rec,  rT);

  for (int c = 0; c < NCHUNK; ++c) {
    int t0 = c * TC;
    conv_x_chunk<<<4096, 256, 0, stream>>>(x, xhc, t0);
    gemm16<<<(B_ * TC / BM) * (NG / BN), 256, 0, stream>>>(xhc, kT, bias, xwl);
    scan_mfma<<<NBLK, 512, 0, stream>>>(xwl, rT, gamma, beta, out, hg, t0);
  }
}

// Round 4
// 3047.073 us; speedup vs baseline: 3.5441x; 3.5441x over previous
//
#include <hip/hip_runtime.h>
#include <hip/hip_bf16.h>
#include <hip/hip_fp16.h>

using half4_t = __attribute__((ext_vector_type(4))) _Float16;
using half8_t = __attribute__((ext_vector_type(8))) _Float16;
using f32x4   = __attribute__((ext_vector_type(4))) float;

#define B_   64
#define T_   2048
#define D_   256
#define U_   256
#define NG   768
#define TC   512
#define NCHUNK (T_/TC)
#define NB   8
#define G_   8
#define PAGE_B 12288   // bytes per (g,t) xw page: 8*768*2

typedef const __attribute__((address_space(1))) void* gptr_t;
typedef __attribute__((address_space(3))) void* lptr_t;

__device__ __forceinline__ float rcpf(float x) { return __builtin_amdgcn_rcpf(x); }

// ---------------- conversions ----------------

__global__ void conv_x_chunk(const float* __restrict__ x, _Float16* __restrict__ xh, int t0) {
  size_t idx = ((size_t)blockIdx.x * 256 + threadIdx.x) * 8;
  int b   = (int)(idx >> 17);
  int rem = (int)(idx & 131071);
  const float4* p = (const float4*)(x + ((size_t)(b * T_ + t0)) * D_ + rem);
  float4 v0 = p[0], v1 = p[1];
  half8_t o;
  o[0] = (_Float16)v0.x; o[1] = (_Float16)v0.y; o[2] = (_Float16)v0.z; o[3] = (_Float16)v0.w;
  o[4] = (_Float16)v1.x; o[5] = (_Float16)v1.y; o[6] = (_Float16)v1.z; o[7] = (_Float16)v1.w;
  *(half8_t*)(xh + idx) = o;
}

// src [256][768] f32 -> dst [768][256] f16 (transpose + convert)
__global__ void conv_T(const float* __restrict__ src, _Float16* __restrict__ dst) {
  int idx = blockIdx.x * 256 + threadIdx.x;
  int d = idx / NG;
  int j = idx - d * NG;
  dst[j * 256 + d] = (_Float16)src[idx];
}

// ---------------- phase 1: xw = x @ kernel + bias -> scattered scan fragments ----------------
#define BM 128
#define BN 128

__global__ __launch_bounds__(256, 2) void gemm16(
    const _Float16* __restrict__ A,
    const _Float16* __restrict__ BT,
    const float* __restrict__ bias,
    _Float16* __restrict__ xwl)
{
  __shared__ alignas(16) _Float16 As[BM * 32];
  __shared__ alignas(16) _Float16 Bs[BN * 32];
  const int tid = threadIdx.x, l = tid & 63, w = tid >> 6;
  const int NT = NG / BN;
  const int mt = blockIdx.x / NT, nt = blockIdx.x % NT;
  const char* Ab = (const char*)A  + (size_t)mt * BM * 512;
  const char* Bb = (const char*)BT + (size_t)nt * BN * 512;
  const int wm = (w & 1) * 64, wn = (w >> 1) * 64;
  f32x4 acc[4][4] = {};

  for (int kt = 0; kt < 8; ++kt) {
    #pragma unroll
    for (int s = 0; s < 2; ++s) {
      int c = tid + s * 256;
      int row = c >> 2, gq = c & 3;
      int gs = gq ^ ((row >> 1) & 3);
      __builtin_amdgcn_global_load_lds(
        (gptr_t)(Ab + (size_t)row * 512 + kt * 64 + gs * 16),
        (lptr_t)((char*)As + c * 16), 16, 0, 0);
    }
    #pragma unroll
    for (int s = 0; s < 2; ++s) {
      int c = tid + s * 256;
      int row = c >> 2, gq = c & 3;
      int gs = gq ^ ((row >> 1) & 3);
      __builtin_amdgcn_global_load_lds(
        (gptr_t)(Bb + (size_t)row * 512 + kt * 64 + gs * 16),
        (lptr_t)((char*)Bs + c * 16), 16, 0, 0);
    }
    __syncthreads();

    half8_t av[4], bv[4];
    #pragma unroll
    for (int m = 0; m < 4; ++m) {
      int row = wm + m * 16 + (l & 15);
      int off = row * 64 + (((l >> 4) ^ ((row >> 1) & 3)) << 4);
      av[m] = *(const half8_t*)((const char*)As + off);
    }
    #pragma unroll
    for (int n = 0; n < 4; ++n) {
      int row = wn + n * 16 + (l & 15);
      int off = row * 64 + (((l >> 4) ^ ((row >> 1) & 3)) << 4);
      bv[n] = *(const half8_t*)((const char*)Bs + off);
    }
    #pragma unroll
    for (int m = 0; m < 4; ++m)
      #pragma unroll
      for (int n = 0; n < 4; ++n)
        acc[m][n] = __builtin_amdgcn_mfma_f32_16x16x32_f16(av[m], bv[n], acc[m][n], 0, 0, 0);
    __syncthreads();
  }

  // epilogue: scatter into scan fragment layout, bias added.
  // elem = (g*512+tloc)*6144 + wv*768 + gate*256 + tt*128 + be*16 + hi*4 + q
  int m0 = mt * BM, n0 = nt * BN;
  #pragma unroll
  for (int m = 0; m < 4; ++m) {
    #pragma unroll
    for (int n = 0; n < 4; ++n) {
      int c = n0 + wn + n * 16 + (l & 15);
      int gate = c >> 8, u = c & 255;
      int wv = u >> 5, tt2 = (u >> 4) & 1, hi2 = (u >> 2) & 3, q2 = u & 3;
      size_t coff = (size_t)wv * 768 + gate * 256 + tt2 * 128 + hi2 * 4 + q2;
      float bc = bias[c];
      #pragma unroll
      for (int q = 0; q < 4; ++q) {
        int arow = m0 + wm + m * 16 + ((l >> 4) * 4 + q);
        int b = arow >> 9, tloc = arow & 511;
        int gg = b >> 3, be2 = b & 7;
        xwl[(size_t)(gg * 512 + tloc) * 6144 + coff + be2 * 16] = (_Float16)(acc[m][n][q] + bc);
      }
    }
  }
}

// ---------------- phase 2: MFMA GRU scan, rec register-resident ----------------
// 8 blocks x 512 thr (8 waves). Block g: batches g*8..g*8+7.
// Wave w owns M-tiles {2w,2w+1, 16+2w,17+2w, 32+2w,33+2w} of rec (48 named half8 frags).
// H (16 cols x 256) in swizzled double-buffered LDS; B-frag = ds_read_b128.
// Gate phase: upper 8 lanes take tt=1 work via shfl_up(8) -> 4 h-updates per lane.

#define DECLK(k) half8_t A0_##k, A1_##k, A2_##k, A3_##k, A4_##k, A5_##k;
#define LOADK(k) A0_##k = rp0[4*k]; A1_##k = rp1[4*k]; A2_##k = rp2[4*k]; \
                 A3_##k = rp3[4*k]; A4_##k = rp4[4*k]; A5_##k = rp5[4*k];
#define MSTEP(k) { half8_t Bf = *(const half8_t*)(hb + (bi << 9) + ((((k)*4 + hi) ^ (bi & 7)) << 4)); \
  a0 = __builtin_amdgcn_mfma_f32_16x16x32_f16(A0_##k, Bf, a0, 0, 0, 0); \
  a1 = __builtin_amdgcn_mfma_f32_16x16x32_f16(A1_##k, Bf, a1, 0, 0, 0); \
  a2 = __builtin_amdgcn_mfma_f32_16x16x32_f16(A2_##k, Bf, a2, 0, 0, 0); \
  a3 = __builtin_amdgcn_mfma_f32_16x16x32_f16(A3_##k, Bf, a3, 0, 0, 0); \
  a4 = __builtin_amdgcn_mfma_f32_16x16x32_f16(A4_##k, Bf, a4, 0, 0, 0); \
  a5 = __builtin_amdgcn_mfma_f32_16x16x32_f16(A5_##k, Bf, a5, 0, 0, 0); }

#define GSTEP(q, hrq) { \
      float sz = __shfl_up(a1[q], 8, 16); \
      float sr = __shfl_up(a3[q], 8, 16); \
      float sh = __shfl_up(a5[q], 8, 16); \
      float az = tte ? sz : a0[q]; \
      float ar = tte ? sr : a2[q]; \
      float ah = tte ? sh : a4[q]; \
      float zp  = az + (float)xz[q]; \
      float rp_ = ar + (float)xr[q]; \
      float hp_ = ah + (float)xh[q]; \
      float zz = rcpf(1.f + __expf(-zp)); \
      float rr = rcpf(1.f + __expf(-rp_)); \
      float y  = rr * (hp_ - hrq) + hrq; \
      float th = 2.f * rcpf(1.f + __expf(-2.f * y)) - 1.f; \
      hrq = zz * (hrq - th) + th; \
      hp[q] = (_Float16)hrq; ov[q] = hrq; }

__global__ __launch_bounds__(512, 2) void scan_mfma(
    const _Float16* __restrict__ xws,
    const _Float16* __restrict__ rT,     // [768][256] f16
    float* __restrict__ out,             // [64][2048][256] f32 (pre-LN h written here)
    float* __restrict__ hg,              // [64][256] f32
    int t0)
{
  const int g = blockIdx.x, tid = threadIdx.x;
  const int w = tid >> 6, l = tid & 63, bi = l & 15, hi = l >> 4;
  const int be = bi & 7, tte = bi >> 3;
  const int u0e = 32 * w + tte * 16 + hi * 4;

  __shared__ alignas(16) _Float16 Hsw[2][16 * 256];   // 2 x 8 KB, granule-swizzled

  { half8_t z8 = {};
    *(half8_t*)((char*)Hsw + tid * 16) = z8;
    *(half8_t*)((char*)Hsw + 8192 + tid * 16) = z8; }

  // rec fragment pointers (A-operand: lane holds rec[mtile*16 + (l&15)][hi*8 + ks*32 ..+8])
  const half8_t* rp0 = (const half8_t*)(rT + (size_t)((2*w + 0)*16 + bi) * 256 + hi * 8);
  const half8_t* rp1 = (const half8_t*)(rT + (size_t)((2*w + 1)*16 + bi) * 256 + hi * 8);
  const half8_t* rp2 = (const half8_t*)(rT + (size_t)((16 + 2*w)*16 + bi) * 256 + hi * 8);
  const half8_t* rp3 = (const half8_t*)(rT + (size_t)((17 + 2*w)*16 + bi) * 256 + hi * 8);
  const half8_t* rp4 = (const half8_t*)(rT + (size_t)((32 + 2*w)*16 + bi) * 256 + hi * 8);
  const half8_t* rp5 = (const half8_t*)(rT + (size_t)((33 + 2*w)*16 + bi) * 256 + hi * 8);

  DECLK(0) DECLK(1) DECLK(2) DECLK(3) DECLK(4) DECLK(5) DECLK(6) DECLK(7)
  LOADK(0) LOADK(1) LOADK(2) LOADK(3) LOADK(4) LOADK(5) LOADK(6) LOADK(7)

  float hr0, hr1, hr2, hr3;
  if (t0 == 0) { hr0 = hr1 = hr2 = hr3 = 0.f; }
  else { f32x4 hv = *(const f32x4*)(hg + (size_t)(g * 8 + be) * 256 + u0e);
         hr0 = hv[0]; hr1 = hv[1]; hr2 = hv[2]; hr3 = hv[3]; }

  const int gran0 = 4 * w + 2 * tte + (hi >> 1);
  const int hwoff = (be << 9) + ((gran0 ^ be) << 4) + ((hi & 1) << 3);

  __syncthreads();   // zero-init done
  { half4_t hp0;
    hp0[0] = (_Float16)hr0; hp0[1] = (_Float16)hr1;
    hp0[2] = (_Float16)hr2; hp0[3] = (_Float16)hr3;
    *(half4_t*)((char*)Hsw + hwoff) = hp0; }

  const char* xp = (const char*)xws + (size_t)g * TC * PAGE_B
                 + ((w * 768 + be * 16 + hi * 4) << 1) + (tte << 8);
  half4_t xz = *(const half4_t*)(xp);
  half4_t xr = *(const half4_t*)(xp + 512);
  half4_t xh = *(const half4_t*)(xp + 1024);

  float* outp = out + ((size_t)(g * 8 + be) * T_ + t0) * U_ + u0e;

  __syncthreads();   // h0 visible

  for (int t = 0; t < TC; ++t) {
    const char* hb = (const char*)Hsw + ((t & 1) << 13);
    f32x4 a0 = {}, a1 = {}, a2 = {}, a3 = {}, a4 = {}, a5 = {};
    MSTEP(0) MSTEP(1) MSTEP(2) MSTEP(3) MSTEP(4) MSTEP(5) MSTEP(6) MSTEP(7)

    half4_t hp; f32x4 ov;
    GSTEP(0, hr0) GSTEP(1, hr1) GSTEP(2, hr2) GSTEP(3, hr3)

    *(half4_t*)((char*)Hsw + (((t & 1) ^ 1) << 13) + hwoff) = hp;
    *(f32x4*)outp = ov;
    outp += U_;

    if (t + 1 < TC) {
      xp += PAGE_B;
      xz = *(const half4_t*)(xp);
      xr = *(const half4_t*)(xp + 512);
      xh = *(const half4_t*)(xp + 1024);
    }
    __syncthreads();
  }

  { f32x4 hv; hv[0] = hr0; hv[1] = hr1; hv[2] = hr2; hv[3] = hr3;
    *(f32x4*)(hg + (size_t)(g * 8 + be) * 256 + u0e) = hv; }
}

// ---------------- phase 3: LayerNorm (in-place on out) ----------------
__global__ __launch_bounds__(256) void ln_rows(
    float* __restrict__ io,
    const float* __restrict__ gamma, const float* __restrict__ beta, int t0)
{
  int rid = blockIdx.x * 4 + (threadIdx.x >> 6);
  int l = threadIdx.x & 63;
  int b = rid >> 9, tl = rid & 511;
  float* p = io + ((size_t)b * T_ + t0 + tl) * U_ + l * 4;
  f32x4 v = *(const f32x4*)p;
  float s  = (v[0] + v[1]) + (v[2] + v[3]);
  float s2 = (v[0]*v[0] + v[1]*v[1]) + (v[2]*v[2] + v[3]*v[3]);
  #pragma unroll
  for (int off = 1; off <= 32; off <<= 1) {
    s  += __shfl_xor(s, off);
    s2 += __shfl_xor(s2, off);
  }
  float mu = s * (1.f / 256.f);
  float var = s2 * (1.f / 256.f) - mu * mu;
  float rs = rsqrtf(var + 1e-6f);
  f32x4 gm = *(const f32x4*)(gamma + l * 4);
  f32x4 bt = *(const f32x4*)(beta + l * 4);
  f32x4 o;
  o[0] = (v[0] - mu) * rs * gm[0] + bt[0];
  o[1] = (v[1] - mu) * rs * gm[1] + bt[1];
  o[2] = (v[2] - mu) * rs * gm[2] + bt[2];
  o[3] = (v[3] - mu) * rs * gm[3] + bt[3];
  *(f32x4*)p = o;
}

// ---------------- launcher ----------------
extern "C" void kernel_launch(void* const* d_in, const int* in_sizes, int n_in,
                              void* d_out, int out_size, void* d_ws, size_t ws_size,
                              hipStream_t stream) {
  const float* x     = (const float*)d_in[0];
  const float* kern  = (const float*)d_in[1];
  const float* rec   = (const float*)d_in[2];
  const float* bias  = (const float*)d_in[3];
  const float* gamma = (const float*)d_in[4];
  const float* beta  = (const float*)d_in[5];
  float* out = (float*)d_out;
  char* ws = (char*)d_ws;

  _Float16* xws = (_Float16*)(ws);                 // 8*512*12288 = 50,331,648 B
  _Float16* xhc = (_Float16*)(ws + 50331648);      // 16,777,216 B
  _Float16* kT  = (_Float16*)(ws + 67108864);      // 393,216 B
  _Float16* rT  = (_Float16*)(ws + 67502080);      // 393,216 B
  float*    hg  = (float*)   (ws + 67895296);      // 65,536 B

  conv_T<<<768, 256, 0, stream>>>(kern, kT);
  conv_T<<<768, 256, 0, stream>>>(rec,  rT);

  for (int c = 0; c < NCHUNK; ++c) {
    int t0 = c * TC;
    conv_x_chunk<<<4096, 256, 0, stream>>>(x, xhc, t0);
    gemm16<<<(B_ * TC / BM) * (NG / BN), 256, 0, stream>>>(xhc, kT, bias, xws);
    scan_mfma<<<G_, 512, 0, stream>>>(xws, rT, out, hg, t0);
    ln_rows<<<(B_ * TC) / 4, 256, 0, stream>>>(out, gamma, beta, t0);
  }
}